// Round 4
// baseline (1860.165 us; speedup 1.0000x reference)
//
#include <hip/hip_runtime.h>

typedef _Float16 half8 __attribute__((ext_vector_type(8)));
typedef float floatx4 __attribute__((ext_vector_type(4)));
typedef float f4v __attribute__((ext_vector_type(4)));

// ---------- helpers ----------

__device__ __forceinline__ unsigned fmap(float f) {
    unsigned u = __float_as_uint(f);
    return (u & 0x80000000u) ? ~u : (u | 0x80000000u);
}
__device__ __forceinline__ float funmap(unsigned m) {
    unsigned u = (m & 0x80000000u) ? (m & 0x7FFFFFFFu) : ~m;
    return __uint_as_float(u);
}

__device__ __forceinline__ unsigned long long shfl_xor_u64(unsigned long long v, int mask) {
    unsigned lo = (unsigned)(v & 0xFFFFFFFFu);
    unsigned hi = (unsigned)(v >> 32);
    lo = __shfl_xor(lo, mask, 64);
    hi = __shfl_xor(hi, mask, 64);
    return (((unsigned long long)hi) << 32) | lo;
}

__device__ __forceinline__ half8 nt_load_h8(const half8* p) {
    return __builtin_nontemporal_load(p);
}
__device__ __forceinline__ f4v nt_load_f4(const f4v* p) {
    return __builtin_nontemporal_load(p);
}
__device__ __forceinline__ void nt_store_h8(half8 v, half8* p) {
    __builtin_nontemporal_store(v, p);
}
__device__ __forceinline__ void nt_store_f4(f4v v, f4v* p) {
    __builtin_nontemporal_store(v, p);
}

// ---------- small kernels ----------

__global__ void init_kernel(unsigned long long* packed, unsigned* maxsim,
                            unsigned long long* minall, unsigned long long* minsame,
                            int Q, int B) {
    int i = blockIdx.x * blockDim.x + threadIdx.x;
    if (i < Q) packed[i] = 0ULL;
    if (i < B) { maxsim[i] = 0u; minall[i] = ~0ULL; minsame[i] = ~0ULL; }
}

// One wave per row: rn[row] = 1 / max(||X[row,:256]||, 1e-12)
__global__ void norms_kernel(const float* __restrict__ X, float* __restrict__ rn, int rows) {
    int w = (blockIdx.x * blockDim.x + threadIdx.x) >> 6;
    int lane = threadIdx.x & 63;
    if (w >= rows) return;
    float4 v = *(const float4*)&X[(long)w * 256 + lane * 4];
    float s = v.x * v.x + v.y * v.y + v.z * v.z + v.w * v.w;
    #pragma unroll
    for (int o = 32; o >= 1; o >>= 1) s += __shfl_xor(s, o, 64);
    if (lane == 0) rn[w] = 1.0f / fmaxf(sqrtf(s), 1e-12f);
}

// Split normalized rows into fp16 hi/lo, stored in MFMA-fragment order:
// element (q,k) -> half8 idx = (qt*8+kc)*64 + fl, elem j
// qt=q>>4, fl = (q&15) | (((k>>3)&3)<<4), kc=k>>5, j=k&7
__global__ void split_a(const float* __restrict__ X, const float* __restrict__ rn,
                        _Float16* __restrict__ Ah, _Float16* __restrict__ Al, int rows) {
    int e = blockIdx.x * 256 + threadIdx.x;
    if (e >= rows * 256) return;
    int q = e >> 8, k = e & 255;
    float v = X[e] * rn[q];
    _Float16 h = (_Float16)v;
    _Float16 l = (_Float16)((v - (float)h) * 2048.0f);
    int qt = q >> 4, r = q & 15, kc = k >> 5, sub = (k >> 3) & 3, j = k & 7;
    int fl = r | (sub << 4);
    long idx = (((long)(qt * 8 + kc)) * 64 + fl) * 8 + j;
    Ah[idx] = h;
    Al[idx] = l;
}

// Normalize + split memory keys into fragment-ordered fp16 hi/lo arrays.
// One block per 16-row m-tile. Streaming: nt loads + nt stores (keep L2 clean).
__global__ __launch_bounds__(256) void prep_b(const float* __restrict__ mk,
                                              _Float16* __restrict__ Bh,
                                              _Float16* __restrict__ Bl, int M) {
    __shared__ float tile[16][272];
    __shared__ float rns[16];
    const int mt = blockIdx.x;
    const int m0 = mt << 4;
    const int t = threadIdx.x;

    #pragma unroll
    for (int i = 0; i < 4; ++i) {
        int flat = i * 256 + t;          // 1024 float4 = 16 rows x 64
        int row = flat >> 6;
        int c4 = (flat & 63) << 2;
        f4v f = (f4v){0.f, 0.f, 0.f, 0.f};
        if (m0 + row < M) f = nt_load_f4((const f4v*)&mk[((long)(m0 + row)) * 256 + c4]);
        *(f4v*)&tile[row][c4] = f;
    }
    __syncthreads();

    const int wave = t >> 6, lane = t & 63;
    #pragma unroll
    for (int rr = 0; rr < 4; ++rr) {
        int row = wave * 4 + rr;
        f4v v = *(f4v*)&tile[row][lane << 2];
        float s = v.x * v.x + v.y * v.y + v.z * v.z + v.w * v.w;
        #pragma unroll
        for (int o = 32; o >= 1; o >>= 1) s += __shfl_xor(s, o, 64);
        if (lane == 0) rns[row] = 1.0f / fmaxf(sqrtf(s), 1e-12f);
    }
    __syncthreads();

    #pragma unroll
    for (int i = 0; i < 2; ++i) {
        int fi = i * 256 + t;            // 512 half8 slots: 8 kc x 64 fl
        int kc = fi >> 6;
        int fl = fi & 63;
        int r = fl & 15, sub = fl >> 4;
        int k0 = (kc << 5) + (sub << 3);
        float rn = rns[r];
        half8 h, l;
        #pragma unroll
        for (int j = 0; j < 8; ++j) {
            float v = tile[r][k0 + j] * rn;
            _Float16 hh = (_Float16)v;
            h[j] = hh;
            l[j] = (_Float16)((v - (float)hh) * 2048.0f);
        }
        long idx = ((long)mt * 8 + kc) * 64 + fl;
        nt_store_h8(h, ((half8*)Bh) + idx);
        nt_store_h8(l, ((half8*)Bl) + idx);
    }
}

// ---------- fused retrieve + update GEMM ----------
// Block: 512 threads (8 waves), owns 4 m-tiles (64 cols). LDS 64 KB -> 2 blocks/CU.
// B staged with nt loads (read-once; keep A L2-resident).
// Atomics filtered by monotone stale-read check (stale value only causes an
// extra atomic, never a missed one).

__global__ __launch_bounds__(512, 4) void retrieve_fused(
    const half8* __restrict__ Ah, const half8* __restrict__ Al,
    const half8* __restrict__ Uh, const half8* __restrict__ Ul,
    const half8* __restrict__ Bh, const half8* __restrict__ Bl,
    const int* __restrict__ mv, const int* __restrict__ lbl,
    unsigned long long* __restrict__ packed,
    unsigned* __restrict__ maxsim, unsigned long long* __restrict__ minall,
    unsigned long long* __restrict__ minsame,
    int M, int Mtiles, int B) {
    __shared__ half8 sB[2][2048];        // [h/l][(nt*8+kc)*64 + lane]  = 64 KB
    const int tid = threadIdx.x;
    const int wave = tid >> 6, lane = tid & 63;
    const int t0 = blockIdx.x << 2;      // first 16-col m-tile of this block
    const int m0 = t0 << 4;

    // stage B tile (fragment order is linear -> coalesced; nt -> no L2 pollution)
    #pragma unroll
    for (int i = 0; i < 4; ++i) {
        int e = i * 512 + tid;           // 2048 half8 entries per array
        int tl = t0 + (e >> 9);
        half8 vh = {0, 0, 0, 0, 0, 0, 0, 0};
        half8 vl = {0, 0, 0, 0, 0, 0, 0, 0};
        if (tl < Mtiles) {
            vh = nt_load_h8(&Bh[(long)t0 * 512 + e]);
            vl = nt_load_h8(&Bl[(long)t0 * 512 + e]);
        }
        sB[0][e] = vh;
        sB[1][e] = vl;
    }
    __syncthreads();

    // ---- retrieve passes ----
    for (int p = 0; p < 8; ++p) {
        const int qt0 = (p * 8 + wave) * 2;
        floatx4 accH[2][4], accM[2][4];
        #pragma unroll
        for (int tq = 0; tq < 2; ++tq)
            #pragma unroll
            for (int nt = 0; nt < 4; ++nt) {
                accH[tq][nt] = (floatx4){0.f, 0.f, 0.f, 0.f};
                accM[tq][nt] = (floatx4){0.f, 0.f, 0.f, 0.f};
            }

        for (int kc = 0; kc < 8; ++kc) {
            half8 a0h = Ah[((long)qt0 * 8 + kc) * 64 + lane];
            half8 a0l = Al[((long)qt0 * 8 + kc) * 64 + lane];
            half8 a1h = Ah[((long)(qt0 + 1) * 8 + kc) * 64 + lane];
            half8 a1l = Al[((long)(qt0 + 1) * 8 + kc) * 64 + lane];
            #pragma unroll
            for (int nt = 0; nt < 4; ++nt) {
                half8 bh = sB[0][(nt * 8 + kc) * 64 + lane];
                half8 bl = sB[1][(nt * 8 + kc) * 64 + lane];
                accH[0][nt] = __builtin_amdgcn_mfma_f32_16x16x32_f16(a0h, bh, accH[0][nt], 0, 0, 0);
                accM[0][nt] = __builtin_amdgcn_mfma_f32_16x16x32_f16(a0h, bl, accM[0][nt], 0, 0, 0);
                accM[0][nt] = __builtin_amdgcn_mfma_f32_16x16x32_f16(a0l, bh, accM[0][nt], 0, 0, 0);
                accH[1][nt] = __builtin_amdgcn_mfma_f32_16x16x32_f16(a1h, bh, accH[1][nt], 0, 0, 0);
                accM[1][nt] = __builtin_amdgcn_mfma_f32_16x16x32_f16(a1h, bl, accM[1][nt], 0, 0, 0);
                accM[1][nt] = __builtin_amdgcn_mfma_f32_16x16x32_f16(a1l, bh, accM[1][nt], 0, 0, 0);
            }
        }

        unsigned long long best[2][4];
        #pragma unroll
        for (int tq = 0; tq < 2; ++tq)
            #pragma unroll
            for (int r = 0; r < 4; ++r) best[tq][r] = 0ULL;

        #pragma unroll
        for (int nt = 0; nt < 4; ++nt) {
            int mi = m0 + (nt << 4) + (lane & 15);
            if (mi < M) {
                unsigned lowbits = ~(unsigned)mi;
                #pragma unroll
                for (int tq = 0; tq < 2; ++tq)
                    #pragma unroll
                    for (int r = 0; r < 4; ++r) {
                        float s = accH[tq][nt][r] + accM[tq][nt][r] * (1.0f / 2048.0f);
                        unsigned long long key =
                            (((unsigned long long)fmap(s)) << 32) | lowbits;
                        if (key > best[tq][r]) best[tq][r] = key;
                    }
            }
        }
        #pragma unroll
        for (int tq = 0; tq < 2; ++tq)
            #pragma unroll
            for (int r = 0; r < 4; ++r) {
                unsigned long long b = best[tq][r];
                #pragma unroll
                for (int o = 1; o < 16; o <<= 1) {
                    unsigned long long ob = shfl_xor_u64(b, o);
                    if (ob > b) b = ob;
                }
                if ((lane & 15) == 0) {
                    int q = (qt0 + tq) * 16 + ((lane >> 4) << 2) + r;
                    if (b > packed[q]) atomicMax(&packed[q], b);
                }
            }
    }

    // ---- fused update pass: wave w handles update q-tile w ----
    if (wave * 16 < B) {
        floatx4 accH[4], accM[4];
        #pragma unroll
        for (int nt = 0; nt < 4; ++nt) {
            accH[nt] = (floatx4){0.f, 0.f, 0.f, 0.f};
            accM[nt] = (floatx4){0.f, 0.f, 0.f, 0.f};
        }
        for (int kc = 0; kc < 8; ++kc) {
            half8 uh = Uh[((long)wave * 8 + kc) * 64 + lane];
            half8 ul_ = Ul[((long)wave * 8 + kc) * 64 + lane];
            #pragma unroll
            for (int nt = 0; nt < 4; ++nt) {
                half8 bh = sB[0][(nt * 8 + kc) * 64 + lane];
                half8 bl = sB[1][(nt * 8 + kc) * 64 + lane];
                accH[nt] = __builtin_amdgcn_mfma_f32_16x16x32_f16(uh, bh, accH[nt], 0, 0, 0);
                accM[nt] = __builtin_amdgcn_mfma_f32_16x16x32_f16(uh, bl, accM[nt], 0, 0, 0);
                accM[nt] = __builtin_amdgcn_mfma_f32_16x16x32_f16(ul_, bh, accM[nt], 0, 0, 0);
            }
        }
        int lb[4];
        #pragma unroll
        for (int r = 0; r < 4; ++r) lb[r] = lbl[(wave << 4) + ((lane >> 4) << 2) + r];

        unsigned bmax[4];
        unsigned long long ball[4], bsame[4];
        #pragma unroll
        for (int r = 0; r < 4; ++r) { bmax[r] = 0u; ball[r] = ~0ULL; bsame[r] = ~0ULL; }

        #pragma unroll
        for (int nt = 0; nt < 4; ++nt) {
            int mi = m0 + (nt << 4) + (lane & 15);
            if (mi < M) {
                int mvv = mv[mi];
                #pragma unroll
                for (int r = 0; r < 4; ++r) {
                    float s = accH[nt][r] + accM[nt][r] * (1.0f / 2048.0f);
                    unsigned ms = fmap(s);
                    if (ms > bmax[r]) bmax[r] = ms;
                    unsigned long long key = (((unsigned long long)ms) << 32) | (unsigned)mi;
                    if (key < ball[r]) ball[r] = key;
                    if (mvv == lb[r] && key < bsame[r]) bsame[r] = key;
                }
            }
        }
        #pragma unroll
        for (int r = 0; r < 4; ++r) {
            unsigned bm = bmax[r];
            unsigned long long ba = ball[r], bs = bsame[r];
            #pragma unroll
            for (int o = 1; o < 16; o <<= 1) {
                unsigned om = __shfl_xor(bm, o, 64);
                if (om > bm) bm = om;
                unsigned long long oa = shfl_xor_u64(ba, o);
                if (oa < ba) ba = oa;
                unsigned long long os = shfl_xor_u64(bs, o);
                if (os < bs) bs = os;
            }
            if ((lane & 15) == 0) {
                int b = (wave << 4) + ((lane >> 4) << 2) + r;
                if (bm > maxsim[b]) atomicMax(&maxsim[b], bm);
                if (ba < minall[b]) atomicMin(&minall[b], ba);
                if (bs < minsame[b]) atomicMin(&minsame[b], bs);
            }
        }
    }
}

// ---------- finish / output kernels ----------

__global__ void finish_retrieve(const unsigned long long* __restrict__ packed,
                                const int* __restrict__ memvals,
                                float* __restrict__ out, int Q) {
    int q = blockIdx.x * blockDim.x + threadIdx.x;
    if (q >= Q) return;
    unsigned long long key = packed[q];
    unsigned m = ~((unsigned)(key & 0xFFFFFFFFu));
    float conf = funmap((unsigned)(key >> 32));
    out[q] = (float)memvals[m];
    out[Q + q] = conf;
}

__global__ void finish_upd(const unsigned* __restrict__ maxsim,
                           const unsigned long long* __restrict__ minall,
                           const unsigned long long* __restrict__ minsame,
                           int* __restrict__ wtgt, int B) {
    __shared__ int tg[256];
    __shared__ unsigned char du[256];
    int b = threadIdx.x;
    int t = -1; bool d = false;
    if (b < B) {
        d = maxsim[b] < fmap(0.8f);
        unsigned long long ks = minsame[b];
        unsigned long long ka = minall[b];
        t = (ks != ~0ULL) ? (int)(ks & 0xFFFFFFFFu) : (int)(ka & 0xFFFFFFFFu);
        tg[b] = t; du[b] = d ? 1 : 0;
    }
    __syncthreads();
    if (b < B) {
        bool win = d;
        if (win)
            for (int b2 = b + 1; b2 < B; ++b2)
                if (du[b2] && tg[b2] == t) { win = false; break; }
        wtgt[b] = win ? t : -1;
    }
}

__global__ void copy_keys(const f4v* __restrict__ src, f4v* __restrict__ dst, long n4) {
    long i = blockIdx.x * (long)blockDim.x + threadIdx.x;
    long stride = (long)gridDim.x * blockDim.x;
    for (; i < n4; i += stride) nt_store_f4(nt_load_f4(&src[i]), &dst[i]);
}

__global__ void copy_vals(const int* __restrict__ src, float* __restrict__ dst, int n) {
    int i = blockIdx.x * blockDim.x + threadIdx.x;
    if (i < n) dst[i] = (float)src[i];
}

__global__ void scatter_kernel(const int* __restrict__ wtgt, const float4* __restrict__ upd4,
                               const int* __restrict__ lbl, float4* __restrict__ keys4,
                               float* __restrict__ vals) {
    int b = blockIdx.x;
    int t = wtgt[b];
    if (t < 0) return;
    int l = threadIdx.x; // 64 threads x float4 = 256 floats
    keys4[(long)t * 64 + l] = upd4[(long)b * 64 + l];
    if (l == 0) vals[t] = (float)lbl[b];
}

// ---------- launch ----------

extern "C" void kernel_launch(void* const* d_in, const int* in_sizes, int n_in,
                              void* d_out, int out_size, void* d_ws, size_t ws_size,
                              hipStream_t stream) {
    const float* qf = (const float*)d_in[0];
    const float* mk = (const float*)d_in[1];
    const int*   mv = (const int*)d_in[2];
    const float* uf = (const float*)d_in[3];
    const int*   ul = (const int*)d_in[4];

    const int D = 256;
    const int Q = in_sizes[0] / D;   // 2048
    const int M = in_sizes[2];       // 100000
    const int B = in_sizes[3] / D;   // 128

    float* out = (float*)d_out;
    float* out_keys = out + 2 * (long)Q;
    float* out_vals = out_keys + (long)M * D;

    // Big fragment arrays for B live inside the out_keys region (exact fit:
    // M*D*2B hi + M*D*2B lo == M*D*4B). copy_keys overwrites them afterwards.
    _Float16* Bh = (_Float16*)out_keys;
    _Float16* Bl = Bh + (size_t)M * D;

    char* w = (char*)d_ws;
    auto carve = [&](size_t bytes) { char* p = w; w += ((bytes + 255) / 256) * 256; return p; };
    float* rq = (float*)carve((size_t)Q * 4);
    float* ru = (float*)carve((size_t)B * 4);
    unsigned long long* packed  = (unsigned long long*)carve((size_t)Q * 8);
    unsigned long long* minall  = (unsigned long long*)carve((size_t)B * 8);
    unsigned long long* minsame = (unsigned long long*)carve((size_t)B * 8);
    unsigned* maxsim = (unsigned*)carve((size_t)B * 4);
    int* wtgt = (int*)carve((size_t)B * 4);
    _Float16* Ah = (_Float16*)carve((size_t)Q * D * 2);
    _Float16* Al = (_Float16*)carve((size_t)Q * D * 2);
    _Float16* Uh = (_Float16*)carve((size_t)B * D * 2);
    _Float16* Ul = (_Float16*)carve((size_t)B * D * 2);

    const int Mtiles = (M + 15) / 16;          // 6250
    const int grid_g = (Mtiles + 3) / 4;       // 1563

    int initN = (Q > B ? Q : B);
    init_kernel<<<(initN + 255) / 256, 256, 0, stream>>>(packed, maxsim, minall, minsame, Q, B);

    norms_kernel<<<(Q + 3) / 4, 256, 0, stream>>>(qf, rq, Q);
    norms_kernel<<<(B + 3) / 4, 256, 0, stream>>>(uf, ru, B);

    split_a<<<(Q * D + 255) / 256, 256, 0, stream>>>(qf, rq, Ah, Al, Q);
    split_a<<<(B * D + 255) / 256, 256, 0, stream>>>(uf, ru, Uh, Ul, B);

    prep_b<<<Mtiles, 256, 0, stream>>>(mk, Bh, Bl, M);

    retrieve_fused<<<grid_g, 512, 0, stream>>>(
        (const half8*)Ah, (const half8*)Al, (const half8*)Uh, (const half8*)Ul,
        (const half8*)Bh, (const half8*)Bl, mv, ul,
        packed, maxsim, minall, minsame, M, Mtiles, B);

    finish_retrieve<<<(Q + 255) / 256, 256, 0, stream>>>(packed, mv, out, Q);
    finish_upd<<<1, B, 0, stream>>>(maxsim, minall, minsame, wtgt, B);

    // After retrieve_fused has consumed Bh/Bl, overwrite the region with the
    // real out_keys contents (same stream -> ordered).
    copy_keys<<<2048, 256, 0, stream>>>((const f4v*)mk, (f4v*)out_keys, (long)M * (D / 4));
    copy_vals<<<(M + 255) / 256, 256, 0, stream>>>(mv, out_vals, M);
    scatter_kernel<<<B, 64, 0, stream>>>(wtgt, (const float4*)uf, ul, (float4*)out_keys, out_vals);
}

// Round 5
// 1162.501 us; speedup vs baseline: 1.6001x; 1.6001x over previous
//
#include <hip/hip_runtime.h>

typedef _Float16 half8 __attribute__((ext_vector_type(8)));
typedef float floatx4 __attribute__((ext_vector_type(4)));
typedef float f4v __attribute__((ext_vector_type(4)));

// ---------- helpers ----------

__device__ __forceinline__ unsigned fmap(float f) {
    unsigned u = __float_as_uint(f);
    return (u & 0x80000000u) ? ~u : (u | 0x80000000u);
}
__device__ __forceinline__ float funmap(unsigned m) {
    unsigned u = (m & 0x80000000u) ? (m & 0x7FFFFFFFu) : ~m;
    return __uint_as_float(u);
}

__device__ __forceinline__ unsigned long long shfl_xor_u64(unsigned long long v, int mask) {
    unsigned lo = (unsigned)(v & 0xFFFFFFFFu);
    unsigned hi = (unsigned)(v >> 32);
    lo = __shfl_xor(lo, mask, 64);
    hi = __shfl_xor(hi, mask, 64);
    return (((unsigned long long)hi) << 32) | lo;
}

__device__ __forceinline__ half8 nt_load_h8(const half8* p) {
    return __builtin_nontemporal_load(p);
}
__device__ __forceinline__ f4v nt_load_f4(const f4v* p) {
    return __builtin_nontemporal_load(p);
}
__device__ __forceinline__ void nt_store_h8(half8 v, half8* p) {
    __builtin_nontemporal_store(v, p);
}
__device__ __forceinline__ void nt_store_f4(f4v v, f4v* p) {
    __builtin_nontemporal_store(v, p);
}

// Load one q-tile's fp32 slice at kc and split to fp16 hi/lo fragments.
// lane holds row (lane&15), k = kc*32 + (lane>>4)*8 + j  (j=0..7)
__device__ __forceinline__ void load_split(const float* __restrict__ X, float rn_,
                                           int row0, int lane, int kc,
                                           half8& h, half8& l) {
    int r = row0 + (lane & 15);
    int k0 = (kc << 5) + ((lane >> 4) << 3);
    const float* p = &X[(long)r * 256 + k0];
    f4v v0 = *(const f4v*)p;
    f4v v1 = *(const f4v*)(p + 4);
    #pragma unroll
    for (int j = 0; j < 4; ++j) {
        float a = v0[j] * rn_;
        _Float16 hh = (_Float16)a;
        h[j] = hh;
        l[j] = (_Float16)((a - (float)hh) * 2048.0f);
        float b = v1[j] * rn_;
        _Float16 hh2 = (_Float16)b;
        h[j + 4] = hh2;
        l[j + 4] = (_Float16)((b - (float)hh2) * 2048.0f);
    }
}

// ---------- small kernels ----------

__global__ void init_kernel(unsigned long long* packed, unsigned* maxsim,
                            unsigned long long* minall, unsigned long long* minsame,
                            int Q, int B) {
    int i = blockIdx.x * blockDim.x + threadIdx.x;
    if (i < Q) packed[i] = 0ULL;
    if (i < B) { maxsim[i] = 0u; minall[i] = ~0ULL; minsame[i] = ~0ULL; }
}

// One wave per row: rn[row] = 1 / max(||X[row,:256]||, 1e-12)
__global__ void norms_kernel(const float* __restrict__ X, float* __restrict__ rn, int rows) {
    int w = (blockIdx.x * blockDim.x + threadIdx.x) >> 6;
    int lane = threadIdx.x & 63;
    if (w >= rows) return;
    float4 v = *(const float4*)&X[(long)w * 256 + lane * 4];
    float s = v.x * v.x + v.y * v.y + v.z * v.z + v.w * v.w;
    #pragma unroll
    for (int o = 32; o >= 1; o >>= 1) s += __shfl_xor(s, o, 64);
    if (lane == 0) rn[w] = 1.0f / fmaxf(sqrtf(s), 1e-12f);
}

// Normalize + split memory keys into fragment-ordered fp16 hi/lo arrays.
// One block per 16-row m-tile. Streaming: nt loads + nt stores (keep L2 clean).
__global__ __launch_bounds__(256) void prep_b(const float* __restrict__ mk,
                                              _Float16* __restrict__ Bh,
                                              _Float16* __restrict__ Bl, int M) {
    __shared__ float tile[16][272];
    __shared__ float rns[16];
    const int mt = blockIdx.x;
    const int m0 = mt << 4;
    const int t = threadIdx.x;

    #pragma unroll
    for (int i = 0; i < 4; ++i) {
        int flat = i * 256 + t;          // 1024 float4 = 16 rows x 64
        int row = flat >> 6;
        int c4 = (flat & 63) << 2;
        f4v f = (f4v){0.f, 0.f, 0.f, 0.f};
        if (m0 + row < M) f = nt_load_f4((const f4v*)&mk[((long)(m0 + row)) * 256 + c4]);
        *(f4v*)&tile[row][c4] = f;
    }
    __syncthreads();

    const int wave = t >> 6, lane = t & 63;
    #pragma unroll
    for (int rr = 0; rr < 4; ++rr) {
        int row = wave * 4 + rr;
        f4v v = *(f4v*)&tile[row][lane << 2];
        float s = v.x * v.x + v.y * v.y + v.z * v.z + v.w * v.w;
        #pragma unroll
        for (int o = 32; o >= 1; o >>= 1) s += __shfl_xor(s, o, 64);
        if (lane == 0) rns[row] = 1.0f / fmaxf(sqrtf(s), 1e-12f);
    }
    __syncthreads();

    #pragma unroll
    for (int i = 0; i < 2; ++i) {
        int fi = i * 256 + t;            // 512 half8 slots: 8 kc x 64 fl
        int kc = fi >> 6;
        int fl = fi & 63;
        int r = fl & 15, sub = fl >> 4;
        int k0 = (kc << 5) + (sub << 3);
        float rn = rns[r];
        half8 h, l;
        #pragma unroll
        for (int j = 0; j < 8; ++j) {
            float v = tile[r][k0 + j] * rn;
            _Float16 hh = (_Float16)v;
            h[j] = hh;
            l[j] = (_Float16)((v - (float)hh) * 2048.0f);
        }
        long idx = ((long)mt * 8 + kc) * 64 + fl;
        nt_store_h8(h, ((half8*)Bh) + idx);
        nt_store_h8(l, ((half8*)Bl) + idx);
    }
}

// ---------- fused retrieve + update GEMM ----------
// Block: 512 threads (8 waves), owns 4 m-tiles (64 cols). LDS 64 KB -> 2 blocks/CU.
// A/U fragments generated on the fly from cacheable d_in (qf/uf) — qf (2 MB)
// stays L2-resident, so per-block A traffic is L2 hits, not HBM.

__global__ __launch_bounds__(512, 4) void retrieve_fused(
    const float* __restrict__ qf, const float* __restrict__ uf,
    const float* __restrict__ rq, const float* __restrict__ ru,
    const half8* __restrict__ Bh, const half8* __restrict__ Bl,
    const int* __restrict__ mv, const int* __restrict__ lbl,
    unsigned long long* __restrict__ packed,
    unsigned* __restrict__ maxsim, unsigned long long* __restrict__ minall,
    unsigned long long* __restrict__ minsame,
    int M, int Mtiles, int B) {
    __shared__ half8 sB[2][2048];        // [h/l][(nt*8+kc)*64 + lane]  = 64 KB
    const int tid = threadIdx.x;
    const int wave = tid >> 6, lane = tid & 63;
    const int t0 = blockIdx.x << 2;      // first 16-col m-tile of this block
    const int m0 = t0 << 4;

    // stage B tile (fragment order is linear -> coalesced; nt -> no L2 pollution)
    #pragma unroll
    for (int i = 0; i < 4; ++i) {
        int e = i * 512 + tid;           // 2048 half8 entries per array
        int tl = t0 + (e >> 9);
        half8 vh = {0, 0, 0, 0, 0, 0, 0, 0};
        half8 vl = {0, 0, 0, 0, 0, 0, 0, 0};
        if (tl < Mtiles) {
            vh = nt_load_h8(&Bh[(long)t0 * 512 + e]);
            vl = nt_load_h8(&Bl[(long)t0 * 512 + e]);
        }
        sB[0][e] = vh;
        sB[1][e] = vl;
    }
    __syncthreads();

    // ---- retrieve passes ----
    for (int p = 0; p < 8; ++p) {
        const int qt0 = (p * 8 + wave) * 2;
        const int q0 = qt0 << 4;
        float rn0 = rq[q0 + (lane & 15)];
        float rn1 = rq[q0 + 16 + (lane & 15)];

        floatx4 accH[2][4], accM[2][4];
        #pragma unroll
        for (int tq = 0; tq < 2; ++tq)
            #pragma unroll
            for (int nt = 0; nt < 4; ++nt) {
                accH[tq][nt] = (floatx4){0.f, 0.f, 0.f, 0.f};
                accM[tq][nt] = (floatx4){0.f, 0.f, 0.f, 0.f};
            }

        for (int kc = 0; kc < 8; ++kc) {
            half8 a0h, a0l, a1h, a1l;
            load_split(qf, rn0, q0, lane, kc, a0h, a0l);
            load_split(qf, rn1, q0 + 16, lane, kc, a1h, a1l);
            #pragma unroll
            for (int nt = 0; nt < 4; ++nt) {
                half8 bh = sB[0][(nt * 8 + kc) * 64 + lane];
                half8 bl = sB[1][(nt * 8 + kc) * 64 + lane];
                accH[0][nt] = __builtin_amdgcn_mfma_f32_16x16x32_f16(a0h, bh, accH[0][nt], 0, 0, 0);
                accM[0][nt] = __builtin_amdgcn_mfma_f32_16x16x32_f16(a0h, bl, accM[0][nt], 0, 0, 0);
                accM[0][nt] = __builtin_amdgcn_mfma_f32_16x16x32_f16(a0l, bh, accM[0][nt], 0, 0, 0);
                accH[1][nt] = __builtin_amdgcn_mfma_f32_16x16x32_f16(a1h, bh, accH[1][nt], 0, 0, 0);
                accM[1][nt] = __builtin_amdgcn_mfma_f32_16x16x32_f16(a1h, bl, accM[1][nt], 0, 0, 0);
                accM[1][nt] = __builtin_amdgcn_mfma_f32_16x16x32_f16(a1l, bh, accM[1][nt], 0, 0, 0);
            }
        }

        unsigned long long best[2][4];
        #pragma unroll
        for (int tq = 0; tq < 2; ++tq)
            #pragma unroll
            for (int r = 0; r < 4; ++r) best[tq][r] = 0ULL;

        #pragma unroll
        for (int nt = 0; nt < 4; ++nt) {
            int mi = m0 + (nt << 4) + (lane & 15);
            if (mi < M) {
                unsigned lowbits = ~(unsigned)mi;
                #pragma unroll
                for (int tq = 0; tq < 2; ++tq)
                    #pragma unroll
                    for (int r = 0; r < 4; ++r) {
                        float s = accH[tq][nt][r] + accM[tq][nt][r] * (1.0f / 2048.0f);
                        unsigned long long key =
                            (((unsigned long long)fmap(s)) << 32) | lowbits;
                        if (key > best[tq][r]) best[tq][r] = key;
                    }
            }
        }
        #pragma unroll
        for (int tq = 0; tq < 2; ++tq)
            #pragma unroll
            for (int r = 0; r < 4; ++r) {
                unsigned long long b = best[tq][r];
                #pragma unroll
                for (int o = 1; o < 16; o <<= 1) {
                    unsigned long long ob = shfl_xor_u64(b, o);
                    if (ob > b) b = ob;
                }
                if ((lane & 15) == 0) {
                    int q = (qt0 + tq) * 16 + ((lane >> 4) << 2) + r;
                    if (b > packed[q]) atomicMax(&packed[q], b);
                }
            }
    }

    // ---- fused update pass: wave w handles update q-tile w ----
    if (wave * 16 < B) {
        const int u0 = wave << 4;
        float rnu = ru[u0 + (lane & 15)];
        floatx4 accH[4], accM[4];
        #pragma unroll
        for (int nt = 0; nt < 4; ++nt) {
            accH[nt] = (floatx4){0.f, 0.f, 0.f, 0.f};
            accM[nt] = (floatx4){0.f, 0.f, 0.f, 0.f};
        }
        for (int kc = 0; kc < 8; ++kc) {
            half8 uh, ul_;
            load_split(uf, rnu, u0, lane, kc, uh, ul_);
            #pragma unroll
            for (int nt = 0; nt < 4; ++nt) {
                half8 bh = sB[0][(nt * 8 + kc) * 64 + lane];
                half8 bl = sB[1][(nt * 8 + kc) * 64 + lane];
                accH[nt] = __builtin_amdgcn_mfma_f32_16x16x32_f16(uh, bh, accH[nt], 0, 0, 0);
                accM[nt] = __builtin_amdgcn_mfma_f32_16x16x32_f16(uh, bl, accM[nt], 0, 0, 0);
                accM[nt] = __builtin_amdgcn_mfma_f32_16x16x32_f16(ul_, bh, accM[nt], 0, 0, 0);
            }
        }
        int lb[4];
        #pragma unroll
        for (int r = 0; r < 4; ++r) lb[r] = lbl[u0 + ((lane >> 4) << 2) + r];

        unsigned bmax[4];
        unsigned long long ball[4], bsame[4];
        #pragma unroll
        for (int r = 0; r < 4; ++r) { bmax[r] = 0u; ball[r] = ~0ULL; bsame[r] = ~0ULL; }

        #pragma unroll
        for (int nt = 0; nt < 4; ++nt) {
            int mi = m0 + (nt << 4) + (lane & 15);
            if (mi < M) {
                int mvv = mv[mi];
                #pragma unroll
                for (int r = 0; r < 4; ++r) {
                    float s = accH[nt][r] + accM[nt][r] * (1.0f / 2048.0f);
                    unsigned ms = fmap(s);
                    if (ms > bmax[r]) bmax[r] = ms;
                    unsigned long long key = (((unsigned long long)ms) << 32) | (unsigned)mi;
                    if (key < ball[r]) ball[r] = key;
                    if (mvv == lb[r] && key < bsame[r]) bsame[r] = key;
                }
            }
        }
        #pragma unroll
        for (int r = 0; r < 4; ++r) {
            unsigned bm = bmax[r];
            unsigned long long ba = ball[r], bs = bsame[r];
            #pragma unroll
            for (int o = 1; o < 16; o <<= 1) {
                unsigned om = __shfl_xor(bm, o, 64);
                if (om > bm) bm = om;
                unsigned long long oa = shfl_xor_u64(ba, o);
                if (oa < ba) ba = oa;
                unsigned long long os = shfl_xor_u64(bs, o);
                if (os < bs) bs = os;
            }
            if ((lane & 15) == 0) {
                int b = u0 + ((lane >> 4) << 2) + r;
                if (bm > maxsim[b]) atomicMax(&maxsim[b], bm);
                if (ba < minall[b]) atomicMin(&minall[b], ba);
                if (bs < minsame[b]) atomicMin(&minsame[b], bs);
            }
        }
    }
}

// ---------- finish / output kernels ----------

__global__ void finish_retrieve(const unsigned long long* __restrict__ packed,
                                const int* __restrict__ memvals,
                                float* __restrict__ out, int Q) {
    int q = blockIdx.x * blockDim.x + threadIdx.x;
    if (q >= Q) return;
    unsigned long long key = packed[q];
    unsigned m = ~((unsigned)(key & 0xFFFFFFFFu));
    float conf = funmap((unsigned)(key >> 32));
    out[q] = (float)memvals[m];
    out[Q + q] = conf;
}

__global__ void finish_upd(const unsigned* __restrict__ maxsim,
                           const unsigned long long* __restrict__ minall,
                           const unsigned long long* __restrict__ minsame,
                           int* __restrict__ wtgt, int B) {
    __shared__ int tg[256];
    __shared__ unsigned char du[256];
    int b = threadIdx.x;
    int t = -1; bool d = false;
    if (b < B) {
        d = maxsim[b] < fmap(0.8f);
        unsigned long long ks = minsame[b];
        unsigned long long ka = minall[b];
        t = (ks != ~0ULL) ? (int)(ks & 0xFFFFFFFFu) : (int)(ka & 0xFFFFFFFFu);
        tg[b] = t; du[b] = d ? 1 : 0;
    }
    __syncthreads();
    if (b < B) {
        bool win = d;
        if (win)
            for (int b2 = b + 1; b2 < B; ++b2)
                if (du[b2] && tg[b2] == t) { win = false; break; }
        wtgt[b] = win ? t : -1;
    }
}

__global__ void copy_keys(const f4v* __restrict__ src, f4v* __restrict__ dst, long n4) {
    long i = blockIdx.x * (long)blockDim.x + threadIdx.x;
    long stride = (long)gridDim.x * blockDim.x;
    for (; i < n4; i += stride) nt_store_f4(nt_load_f4(&src[i]), &dst[i]);
}

__global__ void copy_vals(const int* __restrict__ src, float* __restrict__ dst, int n) {
    int i = blockIdx.x * blockDim.x + threadIdx.x;
    if (i < n) dst[i] = (float)src[i];
}

__global__ void scatter_kernel(const int* __restrict__ wtgt, const float4* __restrict__ upd4,
                               const int* __restrict__ lbl, float4* __restrict__ keys4,
                               float* __restrict__ vals) {
    int b = blockIdx.x;
    int t = wtgt[b];
    if (t < 0) return;
    int l = threadIdx.x; // 64 threads x float4 = 256 floats
    keys4[(long)t * 64 + l] = upd4[(long)b * 64 + l];
    if (l == 0) vals[t] = (float)lbl[b];
}

// ---------- launch ----------

extern "C" void kernel_launch(void* const* d_in, const int* in_sizes, int n_in,
                              void* d_out, int out_size, void* d_ws, size_t ws_size,
                              hipStream_t stream) {
    const float* qf = (const float*)d_in[0];
    const float* mk = (const float*)d_in[1];
    const int*   mv = (const int*)d_in[2];
    const float* uf = (const float*)d_in[3];
    const int*   ul = (const int*)d_in[4];

    const int D = 256;
    const int Q = in_sizes[0] / D;   // 2048
    const int M = in_sizes[2];       // 100000
    const int B = in_sizes[3] / D;   // 128

    float* out = (float*)d_out;
    float* out_keys = out + 2 * (long)Q;
    float* out_vals = out_keys + (long)M * D;

    // B fragment arrays live in the out_keys region (exact fit: M*D*2B hi +
    // M*D*2B lo == M*D*4B). copy_keys overwrites them afterwards.
    _Float16* Bh = (_Float16*)out_keys;
    _Float16* Bl = Bh + (size_t)M * D;

    // Reduction scratch + norms live in the out_vals region (M floats =
    // 400 KB; we use ~28 KB). This memory is normal cacheable VRAM (d_out),
    // unlike d_ws whose reads bypass L2. copy_vals overwrites it at the end.
    char* ov = (char*)out_vals;
    unsigned long long* packed  = (unsigned long long*)(ov);            // 16 KB
    unsigned long long* minall  = (unsigned long long*)(ov + 16384);    // 1 KB
    unsigned long long* minsame = (unsigned long long*)(ov + 17408);    // 1 KB
    unsigned* maxsim            = (unsigned*)(ov + 18432);              // 0.5 KB
    float* rq                   = (float*)(ov + 18944);                 // 8 KB
    float* ru                   = (float*)(ov + 27136);                 // 0.5 KB

    // d_ws only holds atomic-free, rarely-touched data.
    int* wtgt = (int*)d_ws;

    const int Mtiles = (M + 15) / 16;          // 6250
    const int grid_g = (Mtiles + 3) / 4;       // 1563

    int initN = (Q > B ? Q : B);
    init_kernel<<<(initN + 255) / 256, 256, 0, stream>>>(packed, maxsim, minall, minsame, Q, B);

    norms_kernel<<<(Q + 3) / 4, 256, 0, stream>>>(qf, rq, Q);
    norms_kernel<<<(B + 3) / 4, 256, 0, stream>>>(uf, ru, B);

    prep_b<<<Mtiles, 256, 0, stream>>>(mk, Bh, Bl, M);

    retrieve_fused<<<grid_g, 512, 0, stream>>>(
        qf, uf, rq, ru, (const half8*)Bh, (const half8*)Bl, mv, ul,
        packed, maxsim, minall, minsame, M, Mtiles, B);

    finish_retrieve<<<(Q + 255) / 256, 256, 0, stream>>>(packed, mv, out, Q);
    finish_upd<<<1, B, 0, stream>>>(maxsim, minall, minsame, wtgt, B);

    // Overwrite scratch regions with the real outputs (stream-ordered).
    copy_keys<<<2048, 256, 0, stream>>>((const f4v*)mk, (f4v*)out_keys, (long)M * (D / 4));
    copy_vals<<<(M + 255) / 256, 256, 0, stream>>>(mv, out_vals, M);
    scatter_kernel<<<B, 64, 0, stream>>>(wtgt, (const float4*)uf, ul, (float4*)out_keys, out_vals);
}